// Round 16
// baseline (323.457 us; speedup 1.0000x reference)
//
#include <hip/hip_runtime.h>

// ScaledDotProductAttention fwd: out0 = attn output [2,16,2048,64] f32,
// out1 = attn weights [2,16,2048,2048] f32.
// Round 16 = round-13 base (best, 230us) with two contained changes:
//  - rowsum v2: barrier-free, LDS-free, direct-global K frags (round-10
//    pass-2 pattern, validated), kt-split x2 -> 2048 blocks (~8 blocks/CU,
//    TLP-hidden latency like fillBuffer). Writes PARTIAL sums lp2[kc][row]
//    (deterministic); main computes 1/(lp2[0]+lp2[1]).
//  - main: round-13 verbatim + mask word prefetched one kt ahead (was a
//    post-barrier L2-latency stall before the first exp).

typedef __attribute__((ext_vector_type(4))) float f32x4;
typedef __attribute__((ext_vector_type(8))) short s16x8;
typedef __attribute__((ext_vector_type(4))) unsigned short u16x4;
typedef __attribute__((ext_vector_type(8))) unsigned short u16x8;
typedef __attribute__((ext_vector_type(4))) unsigned int u32x4;

#define S_LEN 2048
#define D_DIM 64
#define H_NUM 16
#define B_NUM 2
#define NT    32   // S/64 k-tiles
#define SW    32   // mask words per row (S/64)
#define BHS   (B_NUM * H_NUM * S_LEN)
#define QSCALE 0.18033688011112042f   // 0.125 * log2(e)

__device__ __forceinline__ int swz(int row, int colByte) {
  return row * 128 + (colByte ^ ((row & 7) << 4));
}

__device__ __forceinline__ unsigned short f2bf(float f) {  // RNE f32->bf16
  unsigned int x = __builtin_bit_cast(unsigned int, f);
  x = (x + 0x7FFFu + ((x >> 16) & 1u)) >> 16;
  return (unsigned short)x;
}

__device__ __forceinline__ unsigned cvt_pk_bf16(float lo, float hi) {
  unsigned r;
  asm("v_cvt_pk_bf16_f32 %0, %1, %2" : "=v"(r) : "v"(lo), "v"(hi));
  return r;
}

__device__ __forceinline__ f32x4 mfma16(f32x4 acc, s16x8 a, s16x8 b) {
  return __builtin_amdgcn_mfma_f32_16x16x32_bf16(a, b, acc, 0, 0, 0);
}

// ---------------- merged prep kernel (validated rounds 9-15) ----------------

__global__ __launch_bounds__(256) void prep_kernel(
    const float* __restrict__ Q, const float* __restrict__ K,
    const float* __restrict__ V, const int* __restrict__ m,
    u16x4* __restrict__ Q16, u16x4* __restrict__ K16,
    unsigned short* __restrict__ VT, unsigned long long* __restrict__ bits)
{
  const int blk = blockIdx.x;
  const int tid = threadIdx.x;

  if (blk < 1024) {
    __shared__ unsigned short t[64][72];
    const int bh = blk >> 5;
    const int st = blk & 31;
    const float* src = V + ((size_t)bh * S_LEN + st * 64) * D_DIM;
    const int r0 = tid >> 4;
    const int c  = (tid & 15) * 4;
#pragma unroll
    for (int i = 0; i < 4; ++i) {
      const int r = r0 + i * 16;
      float4 v = *(const float4*)(src + r * D_DIM + c);
      t[c + 0][r] = f2bf(v.x); t[c + 1][r] = f2bf(v.y);
      t[c + 2][r] = f2bf(v.z); t[c + 3][r] = f2bf(v.w);
    }
    __syncthreads();
#pragma unroll
    for (int i = 0; i < 4; ++i) {
      const int idx = tid + i * 256;
      const int d  = idx >> 4;
      const int t0 = (idx & 15) * 4;                       // storage slot base
      const int sp = ((t0 >> 5) & 1) * 32 + ((t0 & 7) >> 2) * 16 + ((t0 >> 3) & 3) * 4;
      u16x4 o = *(const u16x4*)&t[d][sp];                  // 4 consecutive s
      *(u16x4*)(VT + ((size_t)bh * D_DIM + d) * S_LEN + st * 64 + t0) = o;
    }
  } else if (blk < 2048) {
    const int n4 = B_NUM * H_NUM * S_LEN * D_DIM / 4;  // 1048576
    const int step = 1024 * 256;
    for (int i = (blk - 1024) * 256 + tid; i < n4; i += step) {
      float4 q = ((const float4*)Q)[i];
      Q16[i] = u16x4{f2bf(q.x * QSCALE), f2bf(q.y * QSCALE),
                     f2bf(q.z * QSCALE), f2bf(q.w * QSCALE)};
      float4 k = ((const float4*)K)[i];
      K16[i] = u16x4{f2bf(k.x), f2bf(k.y), f2bf(k.z), f2bf(k.w)};
    }
  } else {
    const int total = B_NUM * S_LEN * S_LEN;   // 8388608
    const int step  = 1024 * 256;
    for (int i = (blk - 2048) * 256 + tid; i < total; i += step) {
      unsigned long long b = __ballot(m[i] != 0);
      if ((tid & 63) == 0) bits[i >> 6] = b;
    }
  }
}

// ---------------- rowsum v2: barrier-free, direct-global K, kt-split x2 ----------------
// Round-10 pass-2 fragment pattern (validated): A=K frags from global,
// lane holds S[k=ct*16+g4*4+r][q=wv*16+l15]; mask bit ct*16+g4*4+r.

__global__ __launch_bounds__(256) void attn_rowsum_kernel(
    const unsigned short* __restrict__ Q16, const unsigned short* __restrict__ K16,
    const unsigned long long* __restrict__ Mb, float* __restrict__ lp2)
{
  const int tid  = threadIdx.x;
  const int lane = tid & 63;
  const int wv   = tid >> 6;
  const int l15  = lane & 15;
  const int g4   = lane >> 4;

  const int wg = blockIdx.x;                  // 2048 blocks
  const int lg = (wg & 7) * 256 + (wg >> 3);  // bijective XCD swizzle
  const int kc = lg & 1;                      // kt chunk (16 kts)
  const int qt = (lg >> 1) & 31;
  const int bh = lg >> 6;
  const int b  = bh >> 4;

  const int row = qt * 64 + wv * 16 + l15;

  const unsigned short* Qg16 = Q16 + ((size_t)bh * S_LEN + row) * D_DIM + g4 * 8;
  const unsigned short* Kg16 = K16 + (size_t)bh * S_LEN * D_DIM;
  const unsigned long long* Mrow = Mb + ((size_t)b * S_LEN + row) * SW;

  const s16x8 qa0 = *(const s16x8*)Qg16;
  const s16x8 qa1 = *(const s16x8*)(Qg16 + 32);

  float lps = 0.f;
  const int kt0 = kc * (NT / 2);
  const int kt1 = kt0 + (NT / 2);

  // prefetch K frags for kt0
  s16x8 kb0[4], kb1[4];
#pragma unroll
  for (int ct = 0; ct < 4; ++ct) {
    const unsigned short* kp = Kg16 + (size_t)(kt0 * 64 + ct * 16 + l15) * D_DIM + g4 * 8;
    kb0[ct] = *(const s16x8*)kp;
    kb1[ct] = *(const s16x8*)(kp + 32);
  }
  unsigned long long mw = Mrow[kt0];

  for (int kt = kt0; kt < kt1; ++kt) {
    const int ktn = (kt + 1 < kt1) ? kt + 1 : kt;
    s16x8 nk0[4], nk1[4];
#pragma unroll
    for (int ct = 0; ct < 4; ++ct) {
      const unsigned short* kp = Kg16 + (size_t)(ktn * 64 + ct * 16 + l15) * D_DIM + g4 * 8;
      nk0[ct] = *(const s16x8*)kp;
      nk1[ct] = *(const s16x8*)(kp + 32);
    }
    const unsigned long long mwn = Mrow[ktn];

    f32x4 sacc[4];
#pragma unroll
    for (int i = 0; i < 4; ++i) sacc[i] = f32x4{0.f, 0.f, 0.f, 0.f};
#pragma unroll
    for (int ct = 0; ct < 4; ++ct) {
      sacc[ct] = mfma16(sacc[ct], kb0[ct], qa0);
      sacc[ct] = mfma16(sacc[ct], kb1[ct], qa1);
    }

#pragma unroll
    for (int ct = 0; ct < 4; ++ct) {
#pragma unroll
      for (int r = 0; r < 4; ++r) {
        float e = __builtin_amdgcn_exp2f(sacc[ct][r]);
        lps += ((mw >> (ct * 16 + g4 * 4 + r)) & 1ull) ? e : 0.f;
      }
    }
    mw = mwn;
#pragma unroll
    for (int ct = 0; ct < 4; ++ct) { kb0[ct] = nk0[ct]; kb1[ct] = nk1[ct]; }
  }

  lps += __shfl_xor(lps, 16);
  lps += __shfl_xor(lps, 32);
  if (g4 == 0) lp2[(size_t)kc * BHS + (size_t)bh * S_LEN + row] = lps;
}

// ---------------- main kernel: round-13 verbatim + mask prefetch ----------------

__global__ __launch_bounds__(256) void attn_main_kernel(
    const unsigned short* __restrict__ Q16, const unsigned short* __restrict__ K16,
    const unsigned short* __restrict__ VT16, const unsigned long long* __restrict__ Mb,
    const float* __restrict__ lp2, float* __restrict__ Op, float* __restrict__ Wp)
{
  const int tid  = threadIdx.x;
  const int lane = tid & 63;
  const int wv   = tid >> 6;
  const int l15  = lane & 15;
  const int g4   = lane >> 4;

  const int wg = blockIdx.x;                 // 1024 blocks
  const int lg = (wg & 7) * 128 + (wg >> 3); // bijective XCD swizzle
  const int qt = lg & 31;
  const int bh = lg >> 5;
  const int b  = bh >> 4;

  __shared__ __align__(16) char lds[32768];
  char* Kbuf = lds;                          // 2 x [64 k][64 d] bf16 swz
  char* Vbuf = lds + 16384;                  // 2 x [64 d][64 s-perm] bf16 swz

  const unsigned short* Qg16 = Q16 + ((size_t)bh * S_LEN + qt * 64 + wv * 16 + l15) * D_DIM + g4 * 8;
  const unsigned short* Kg16 = K16 + (size_t)bh * S_LEN * D_DIM;
  const unsigned short* Vg   = VT16 + (size_t)bh * D_DIM * S_LEN;
  float* Og = Op + ((size_t)bh * S_LEN + qt * 64) * D_DIM;
  float* Wrow = Wp + ((size_t)bh * S_LEN + qt * 64 + wv * 16 + l15) * S_LEN;
  const unsigned long long* Mrow = Mb + ((size_t)b * S_LEN + qt * 64 + wv * 16 + l15) * SW;
  const float* lpA = lp2 + (size_t)bh * S_LEN + qt * 64;
  const float* lpB = lpA + BHS;

  const s16x8 qa0 = *(const s16x8*)Qg16;
  const s16x8 qa1 = *(const s16x8*)(Qg16 + 32);

  const float lpr = 1.0f / (lpA[wv * 16 + l15] + lpB[wv * 16 + l15]);
  float lpn[4];
#pragma unroll
  for (int r = 0; r < 4; ++r)
    lpn[r] = 1.0f / (lpA[wv * 16 + g4 * 4 + r] + lpB[wv * 16 + g4 * 4 + r]);

  f32x4 oacc[4];
#pragma unroll
  for (int i = 0; i < 4; ++i) oacc[i] = f32x4{0.f, 0.f, 0.f, 0.f};

  const int sr  = tid >> 3;   // 0..31: rows {sr, sr+32}
  const int ss  = tid & 7;
  const int ssb = ss * 16;

  // ---- prologue: stage tile 0 into buffer 0 ----
  {
    u16x8 k0 = *(const u16x8*)(Kg16 + (size_t)sr * D_DIM + ss * 8);
    u16x8 k1 = *(const u16x8*)(Kg16 + (size_t)(sr + 32) * D_DIM + ss * 8);
    u16x8 v0 = *(const u16x8*)(Vg + (size_t)sr * S_LEN + ss * 8);
    u16x8 v1 = *(const u16x8*)(Vg + (size_t)(sr + 32) * S_LEN + ss * 8);
    *(u16x8*)(Kbuf + swz(sr, ssb))      = k0;
    *(u16x8*)(Kbuf + swz(sr + 32, ssb)) = k1;
    *(u16x8*)(Vbuf + swz(sr, ssb))      = v0;
    *(u16x8*)(Vbuf + swz(sr + 32, ssb)) = v1;
  }
  unsigned long long mw = Mrow[0];
  __syncthreads();

  int cur = 0;
  for (int kt = 0; kt < NT; ++kt) {
    const int ktn = (kt + 1 < NT) ? kt + 1 : kt;
    u16x8 kr0 = *(const u16x8*)(Kg16 + (size_t)(ktn * 64 + sr) * D_DIM + ss * 8);
    u16x8 kr1 = *(const u16x8*)(Kg16 + (size_t)(ktn * 64 + sr + 32) * D_DIM + ss * 8);
    u16x8 vr0 = *(const u16x8*)(Vg + (size_t)sr * S_LEN + ktn * 64 + ss * 8);
    u16x8 vr1 = *(const u16x8*)(Vg + (size_t)(sr + 32) * S_LEN + ktn * 64 + ss * 8);
    const unsigned long long mwn = Mrow[ktn];   // mask prefetched with K/V
    __builtin_amdgcn_sched_barrier(0);   // pin load issue above compute

    char* Kc = Kbuf + cur * 8192;
    char* Vc = Vbuf + cur * 8192;

    // SWAPPED QK^T: lane holds S[k=ct*16+g4*4+r][q=qt*64+wv*16+l15]
    f32x4 sacc[4];
#pragma unroll
    for (int i = 0; i < 4; ++i) sacc[i] = f32x4{0.f, 0.f, 0.f, 0.f};
#pragma unroll
    for (int ct = 0; ct < 4; ++ct) {
      s16x8 b0 = *(const s16x8*)(Kc + swz(ct * 16 + l15, g4 * 16));
      s16x8 b1 = *(const s16x8*)(Kc + swz(ct * 16 + l15, g4 * 16 + 64));
      sacc[ct] = mfma16(sacc[ct], b0, qa0);
      sacc[ct] = mfma16(sacc[ct], b1, qa1);
    }

    // exp + mask; W store (normalized, overlaps PV); pack P frags
    unsigned pw[8];
#pragma unroll
    for (int ct = 0; ct < 4; ++ct) {
      float e0 = __builtin_amdgcn_exp2f(sacc[ct][0]);
      float e1 = __builtin_amdgcn_exp2f(sacc[ct][1]);
      float e2 = __builtin_amdgcn_exp2f(sacc[ct][2]);
      float e3 = __builtin_amdgcn_exp2f(sacc[ct][3]);
      e0 = ((mw >> (ct * 16 + g4 * 4 + 0)) & 1ull) ? e0 : 0.f;
      e1 = ((mw >> (ct * 16 + g4 * 4 + 1)) & 1ull) ? e1 : 0.f;
      e2 = ((mw >> (ct * 16 + g4 * 4 + 2)) & 1ull) ? e2 : 0.f;
      e3 = ((mw >> (ct * 16 + g4 * 4 + 3)) & 1ull) ? e3 : 0.f;
      f32x4 w = {e0 * lpr, e1 * lpr, e2 * lpr, e3 * lpr};
      __builtin_nontemporal_store(w,
          (f32x4*)(Wrow + (size_t)kt * 64 + ct * 16 + g4 * 4));
      pw[2 * ct]     = cvt_pk_bf16(e0, e1);
      pw[2 * ct + 1] = cvt_pk_bf16(e2, e3);
    }
    const s16x8 pa0 = __builtin_bit_cast(s16x8, u32x4{pw[0], pw[1], pw[2], pw[3]});
    const s16x8 pa1 = __builtin_bit_cast(s16x8, u32x4{pw[4], pw[5], pw[6], pw[7]});

    // PV: A=P (unnormalized; l folded at O store), B=V^T (sigma-permuted)
#pragma unroll
    for (int ct = 0; ct < 4; ++ct) {
      s16x8 v0 = *(const s16x8*)(Vc + swz(ct * 16 + l15, g4 * 16));
      s16x8 v1 = *(const s16x8*)(Vc + swz(ct * 16 + l15, g4 * 16 + 64));
      oacc[ct] = mfma16(oacc[ct], pa0, v0);
      oacc[ct] = mfma16(oacc[ct], pa1, v1);
    }

    char* Kn = Kbuf + (cur ^ 1) * 8192;
    char* Vn = Vbuf + (cur ^ 1) * 8192;
    *(u16x8*)(Kn + swz(sr, ssb))      = kr0;
    *(u16x8*)(Kn + swz(sr + 32, ssb)) = kr1;
    *(u16x8*)(Vn + swz(sr, ssb))      = vr0;
    *(u16x8*)(Vn + swz(sr + 32, ssb)) = vr1;
    mw = mwn;
    __syncthreads();
    cur ^= 1;
  }

  // O store: oacc[ct][r] = O[q=wv*16+g4*4+r][d=ct*16+l15] (x 1/l)
#pragma unroll
  for (int ct = 0; ct < 4; ++ct)
#pragma unroll
    for (int r = 0; r < 4; ++r)
      Og[(size_t)(wv * 16 + g4 * 4 + r) * D_DIM + ct * 16 + l15] = oacc[ct][r] * lpn[r];
}

// ---------------- fallback (fp32 inputs, LDS-staged, int mask) ----------------

__global__ __launch_bounds__(256) void attn_fwd_kernel(
    const float* __restrict__ Qp, const float* __restrict__ Kp, const float* __restrict__ Vp,
    const int* __restrict__ Mi, float* __restrict__ Op, float* __restrict__ Wp)
{
  const int tid  = threadIdx.x;
  const int lane = tid & 63;
  const int wv   = tid >> 6;
  const int l15  = lane & 15;
  const int g4   = lane >> 4;

  const int wg = blockIdx.x;
  const int lg = (wg & 7) * 128 + (wg >> 3);
  const int qt = lg & 31;
  const int bh = lg >> 5;
  const int b  = bh >> 4;

  __shared__ __align__(16) char lds[32768];
  char* Qs  = lds;
  char* Ks  = lds + 8192;
  char* VTs = lds + 16384;
  char* Ps  = lds + 24576 + (wv << 11);

  const float* Qg = Qp + ((size_t)bh * S_LEN + qt * 64) * D_DIM;
  const float* Kg = Kp + (size_t)bh * S_LEN * D_DIM;
  const float* Vg = Vp + (size_t)bh * S_LEN * D_DIM;
  float* Og = Op + ((size_t)bh * S_LEN + qt * 64) * D_DIM;
  float* Wg = Wp + ((size_t)bh * S_LEN + qt * 64) * S_LEN;
  const int* Mig = Mi + ((size_t)b * S_LEN + qt * 64) * S_LEN;

  {
    const int r0 = tid >> 4;
    const int c  = (tid & 15) * 4;
#pragma unroll
    for (int i = 0; i < 4; ++i) {
      const int r = r0 + i * 16;
      float4 v = *(const float4*)(Qg + r * D_DIM + c);
      ushort4 p; p.x = f2bf(v.x); p.y = f2bf(v.y); p.z = f2bf(v.z); p.w = f2bf(v.w);
      *(ushort4*)(Qs + swz(r, c * 2)) = p;
    }
  }
  __syncthreads();
  const s16x8 qa0 = *(const s16x8*)(Qs + swz(wv * 16 + l15, g4 * 16));
  const s16x8 qa1 = *(const s16x8*)(Qs + swz(wv * 16 + l15, g4 * 16 + 64));

  f32x4 oacc[4];
#pragma unroll
  for (int i = 0; i < 4; ++i) oacc[i] = f32x4{0.f, 0.f, 0.f, 0.f};
  float lp[4] = {0.f, 0.f, 0.f, 0.f};

  const int qrow = wv * 16 + g4 * 4;

  for (int kt = 0; kt < NT; ++kt) {
    __syncthreads();
    {
      const int r0 = tid >> 4;
      const int c  = (tid & 15) * 4;
      const float* Kt = Kg + kt * 64 * D_DIM;
#pragma unroll
      for (int i = 0; i < 4; ++i) {
        const int r = r0 + i * 16;
        float4 v = *(const float4*)(Kt + r * D_DIM + c);
        ushort4 p; p.x = f2bf(v.x); p.y = f2bf(v.y); p.z = f2bf(v.z); p.w = f2bf(v.w);
        *(ushort4*)(Ks + swz(r, c * 2)) = p;
      }
      const float* Vt = Vg + kt * 64 * D_DIM;
#pragma unroll
      for (int i = 0; i < 2; ++i) {
        const int rr = (tid >> 4) * 2 + i * 32;
        float4 a  = *(const float4*)(Vt + rr * D_DIM + c);
        float4 bq = *(const float4*)(Vt + (rr + 1) * D_DIM + c);
        const float av[4] = {a.x, a.y, a.z, a.w};
        const float bv[4] = {bq.x, bq.y, bq.z, bq.w};
#pragma unroll
        for (int j = 0; j < 4; ++j) {
          unsigned pk = (unsigned)f2bf(av[j]) | ((unsigned)f2bf(bv[j]) << 16);
          *(unsigned*)(VTs + swz(c + j, rr * 2)) = pk;
        }
      }
    }
    __syncthreads();

    f32x4 sacc[4];
#pragma unroll
    for (int i = 0; i < 4; ++i) sacc[i] = f32x4{0.f, 0.f, 0.f, 0.f};
#pragma unroll
    for (int ct = 0; ct < 4; ++ct) {
      s16x8 b0 = *(const s16x8*)(Ks + swz(ct * 16 + l15, g4 * 16));
      s16x8 b1 = *(const s16x8*)(Ks + swz(ct * 16 + l15, g4 * 16 + 64));
      sacc[ct] = mfma16(sacc[ct], qa0, b0);
      sacc[ct] = mfma16(sacc[ct], qa1, b1);
    }

#pragma unroll
    for (int ct = 0; ct < 4; ++ct) {
#pragma unroll
      for (int r = 0; r < 4; ++r) {
        float e = __expf(sacc[ct][r] * 0.125f);
        bool keep = Mig[(size_t)(qrow + r) * S_LEN + kt * 64 + ct * 16 + l15] != 0;
        e = keep ? e : 0.f;
        lp[r] += e;
        *(unsigned short*)(Ps + swz(g4 * 4 + r, (ct * 16 + l15) * 2)) = f2bf(e);
      }
    }
    asm volatile("s_waitcnt lgkmcnt(0)" ::: "memory");
    __builtin_amdgcn_sched_barrier(0);

    const s16x8 pa0 = *(const s16x8*)(Ps + swz(l15, g4 * 16));
    const s16x8 pa1 = *(const s16x8*)(Ps + swz(l15, g4 * 16 + 64));
#pragma unroll
    for (int ct = 0; ct < 4; ++ct) {
      s16x8 v0 = *(const s16x8*)(VTs + swz(ct * 16 + l15, g4 * 16));
      s16x8 v1 = *(const s16x8*)(VTs + swz(ct * 16 + l15, g4 * 16 + 64));
      oacc[ct] = mfma16(oacc[ct], pa0, v0);
      oacc[ct] = mfma16(oacc[ct], pa1, v1);
    }
  }

#pragma unroll
  for (int r = 0; r < 4; ++r) {
    float v = lp[r];
    v += __shfl_xor(v, 1);
    v += __shfl_xor(v, 2);
    v += __shfl_xor(v, 4);
    v += __shfl_xor(v, 8);
    lp[r] = 1.0f / v;
  }

#pragma unroll
  for (int ct = 0; ct < 4; ++ct)
#pragma unroll
    for (int r = 0; r < 4; ++r)
      Og[(size_t)(qrow + r) * D_DIM + ct * 16 + l15] = oacc[ct][r] * lp[r];

  for (int kt = 0; kt < NT; ++kt) {
    __syncthreads();
    {
      const int r0 = tid >> 4;
      const int c  = (tid & 15) * 4;
      const float* Kt = Kg + kt * 64 * D_DIM;
#pragma unroll
      for (int i = 0; i < 4; ++i) {
        const int r = r0 + i * 16;
        float4 v = *(const float4*)(Kt + r * D_DIM + c);
        ushort4 p; p.x = f2bf(v.x); p.y = f2bf(v.y); p.z = f2bf(v.z); p.w = f2bf(v.w);
        *(ushort4*)(Ks + swz(r, c * 2)) = p;
      }
    }
    __syncthreads();

    f32x4 sacc[4];
#pragma unroll
    for (int i = 0; i < 4; ++i) sacc[i] = f32x4{0.f, 0.f, 0.f, 0.f};
#pragma unroll
    for (int ct = 0; ct < 4; ++ct) {
      s16x8 b0 = *(const s16x8*)(Ks + swz(ct * 16 + l15, g4 * 16));
      s16x8 b1 = *(const s16x8*)(Ks + swz(ct * 16 + l15, g4 * 16 + 64));
      sacc[ct] = mfma16(sacc[ct], qa0, b0);
      sacc[ct] = mfma16(sacc[ct], qa1, b1);
    }

#pragma unroll
    for (int ct = 0; ct < 4; ++ct) {
#pragma unroll
      for (int r = 0; r < 4; ++r) {
        float e = __expf(sacc[ct][r] * 0.125f);
        bool keep = Mig[(size_t)(qrow + r) * S_LEN + kt * 64 + ct * 16 + l15] != 0;
        e = keep ? e : 0.f;
        __builtin_nontemporal_store(e * lp[r],
            Wg + (size_t)(qrow + r) * S_LEN + kt * 64 + ct * 16 + l15);
      }
    }
  }
}

extern "C" void kernel_launch(void* const* d_in, const int* in_sizes, int n_in,
                              void* d_out, int out_size, void* d_ws, size_t ws_size,
                              hipStream_t stream) {
  (void)in_sizes; (void)n_in; (void)out_size;
  const float* Q   = (const float*)d_in[0];
  const float* K   = (const float*)d_in[1];
  const float* V   = (const float*)d_in[2];
  const int* mask  = (const int*)d_in[3];
  float* Out = (float*)d_out;
  float* W   = Out + (size_t)B_NUM * H_NUM * S_LEN * D_DIM;

  const size_t bits_bytes = (size_t)(B_NUM * S_LEN * S_LEN / 64) * 8;      // 1 MiB
  const size_t t16_bytes  = (size_t)B_NUM * H_NUM * S_LEN * D_DIM * 2;     // 8 MiB
  const size_t lp2_bytes  = (size_t)2 * BHS * 4;                           // 512 KiB
  unsigned long long* bits = (unsigned long long*)d_ws;

  if (ws_size >= bits_bytes + 3 * t16_bytes + lp2_bytes) {
    unsigned short* Q16 = (unsigned short*)((char*)d_ws + bits_bytes);
    unsigned short* K16 = Q16 + t16_bytes / 2;
    unsigned short* VT  = K16 + t16_bytes / 2;
    float* lp2 = (float*)((char*)d_ws + bits_bytes + 3 * t16_bytes);
    prep_kernel<<<3072, 256, 0, stream>>>(Q, K, V, mask,
                                          (u16x4*)Q16, (u16x4*)K16, VT, bits);
    attn_rowsum_kernel<<<2048, 256, 0, stream>>>(Q16, K16, bits, lp2);
    attn_main_kernel<<<1024, 256, 0, stream>>>(Q16, K16, VT, bits, lp2, Out, W);
  } else {
    attn_fwd_kernel<<<1024, 256, 0, stream>>>(Q, K, V, mask, Out, W);
  }
}

// Round 17
// 230.188 us; speedup vs baseline: 1.4052x; 1.4052x over previous
//
#include <hip/hip_runtime.h>

// ScaledDotProductAttention fwd: out0 = attn output [2,16,2048,64] f32,
// out1 = attn weights [2,16,2048,2048] f32.
// Round 17: REVERT to round-13 (best validated, 230us).
//  - prep: V transpose (sigma-permuted) + Q/K->bf16 (Q pre-scaled by
//    0.125*log2e) + mask bit-pack, one merged kernel.
//  - rowsum: LDS-staged K dbuf, swapped QK -> exp -> 1/l per q row.
//  - main: LDS-staged K+V dbuf, swapped QK, in-register softmax (cvt_pk
//    P-frags), W f32x4 NT stores (normalized) overlapping PV MFMA, O at end.

typedef __attribute__((ext_vector_type(4))) float f32x4;
typedef __attribute__((ext_vector_type(8))) short s16x8;
typedef __attribute__((ext_vector_type(4))) unsigned short u16x4;
typedef __attribute__((ext_vector_type(8))) unsigned short u16x8;
typedef __attribute__((ext_vector_type(4))) unsigned int u32x4;

#define S_LEN 2048
#define D_DIM 64
#define H_NUM 16
#define B_NUM 2
#define NT    32   // S/64 k-tiles
#define SW    32   // mask words per row (S/64)
#define QSCALE 0.18033688011112042f   // 0.125 * log2(e)

__device__ __forceinline__ int swz(int row, int colByte) {
  return row * 128 + (colByte ^ ((row & 7) << 4));
}

__device__ __forceinline__ unsigned short f2bf(float f) {  // RNE f32->bf16
  unsigned int x = __builtin_bit_cast(unsigned int, f);
  x = (x + 0x7FFFu + ((x >> 16) & 1u)) >> 16;
  return (unsigned short)x;
}

__device__ __forceinline__ unsigned cvt_pk_bf16(float lo, float hi) {
  unsigned r;
  asm("v_cvt_pk_bf16_f32 %0, %1, %2" : "=v"(r) : "v"(lo), "v"(hi));
  return r;
}

__device__ __forceinline__ f32x4 mfma16(f32x4 acc, s16x8 a, s16x8 b) {
  return __builtin_amdgcn_mfma_f32_16x16x32_bf16(a, b, acc, 0, 0, 0);
}

// ---------------- merged prep kernel ----------------

__global__ __launch_bounds__(256) void prep_kernel(
    const float* __restrict__ Q, const float* __restrict__ K,
    const float* __restrict__ V, const int* __restrict__ m,
    u16x4* __restrict__ Q16, u16x4* __restrict__ K16,
    unsigned short* __restrict__ VT, unsigned long long* __restrict__ bits)
{
  const int blk = blockIdx.x;
  const int tid = threadIdx.x;

  if (blk < 1024) {
    __shared__ unsigned short t[64][72];
    const int bh = blk >> 5;
    const int st = blk & 31;
    const float* src = V + ((size_t)bh * S_LEN + st * 64) * D_DIM;
    const int r0 = tid >> 4;
    const int c  = (tid & 15) * 4;
#pragma unroll
    for (int i = 0; i < 4; ++i) {
      const int r = r0 + i * 16;
      float4 v = *(const float4*)(src + r * D_DIM + c);
      t[c + 0][r] = f2bf(v.x); t[c + 1][r] = f2bf(v.y);
      t[c + 2][r] = f2bf(v.z); t[c + 3][r] = f2bf(v.w);
    }
    __syncthreads();
#pragma unroll
    for (int i = 0; i < 4; ++i) {
      const int idx = tid + i * 256;
      const int d  = idx >> 4;
      const int t0 = (idx & 15) * 4;                       // storage slot base
      const int sp = ((t0 >> 5) & 1) * 32 + ((t0 & 7) >> 2) * 16 + ((t0 >> 3) & 3) * 4;
      u16x4 o = *(const u16x4*)&t[d][sp];                  // 4 consecutive s
      *(u16x4*)(VT + ((size_t)bh * D_DIM + d) * S_LEN + st * 64 + t0) = o;
    }
  } else if (blk < 2048) {
    const int n4 = B_NUM * H_NUM * S_LEN * D_DIM / 4;  // 1048576
    const int step = 1024 * 256;
    for (int i = (blk - 1024) * 256 + tid; i < n4; i += step) {
      float4 q = ((const float4*)Q)[i];
      Q16[i] = u16x4{f2bf(q.x * QSCALE), f2bf(q.y * QSCALE),
                     f2bf(q.z * QSCALE), f2bf(q.w * QSCALE)};
      float4 k = ((const float4*)K)[i];
      K16[i] = u16x4{f2bf(k.x), f2bf(k.y), f2bf(k.z), f2bf(k.w)};
    }
  } else {
    const int total = B_NUM * S_LEN * S_LEN;   // 8388608
    const int step  = 1024 * 256;
    for (int i = (blk - 2048) * 256 + tid; i < total; i += step) {
      unsigned long long b = __ballot(m[i] != 0);
      if ((tid & 63) == 0) bits[i >> 6] = b;
    }
  }
}

// ---------------- rowsum kernel: 1/l per q row ----------------

__global__ __launch_bounds__(256) void attn_rowsum_kernel(
    const unsigned short* __restrict__ Q16, const unsigned short* __restrict__ K16,
    const unsigned long long* __restrict__ Mb, float* __restrict__ lpq)
{
  const int tid  = threadIdx.x;
  const int lane = tid & 63;
  const int wv   = tid >> 6;
  const int l15  = lane & 15;
  const int g4   = lane >> 4;

  const int wg = blockIdx.x;                 // 1024 blocks
  const int lg = (wg & 7) * 128 + (wg >> 3); // bijective XCD swizzle
  const int qt = lg & 31;
  const int bh = lg >> 5;
  const int b  = bh >> 4;

  __shared__ __align__(16) char Kbuf[16384];  // 2 x [64 k][64 d] bf16 swz

  const unsigned short* Qg16 = Q16 + ((size_t)bh * S_LEN + qt * 64 + wv * 16 + l15) * D_DIM + g4 * 8;
  const unsigned short* Kg16 = K16 + (size_t)bh * S_LEN * D_DIM;
  float* lpg = lpq + (size_t)bh * S_LEN + qt * 64;
  const unsigned long long* Mg = Mb + ((size_t)b * S_LEN + qt * 64) * SW;

  const s16x8 qa0 = *(const s16x8*)Qg16;
  const s16x8 qa1 = *(const s16x8*)(Qg16 + 32);

  float lps = 0.f;

  const int sr  = tid >> 3;   // 0..31: rows {sr, sr+32}
  const int ss  = tid & 7;
  const int ssb = ss * 16;

  {
    u16x8 k0 = *(const u16x8*)(Kg16 + (size_t)sr * D_DIM + ss * 8);
    u16x8 k1 = *(const u16x8*)(Kg16 + (size_t)(sr + 32) * D_DIM + ss * 8);
    *(u16x8*)(Kbuf + swz(sr, ssb))      = k0;
    *(u16x8*)(Kbuf + swz(sr + 32, ssb)) = k1;
  }
  __syncthreads();

  int cur = 0;
  for (int kt = 0; kt < NT; ++kt) {
    const int ktn = (kt + 1 < NT) ? kt + 1 : kt;
    u16x8 kr0 = *(const u16x8*)(Kg16 + (size_t)(ktn * 64 + sr) * D_DIM + ss * 8);
    u16x8 kr1 = *(const u16x8*)(Kg16 + (size_t)(ktn * 64 + sr + 32) * D_DIM + ss * 8);
    __builtin_amdgcn_sched_barrier(0);

    char* Kc = Kbuf + cur * 8192;
    const unsigned long long mw = Mg[(wv * 16 + l15) * SW + kt];

    f32x4 sacc[4];
#pragma unroll
    for (int i = 0; i < 4; ++i) sacc[i] = f32x4{0.f, 0.f, 0.f, 0.f};
#pragma unroll
    for (int ct = 0; ct < 4; ++ct) {
      s16x8 b0 = *(const s16x8*)(Kc + swz(ct * 16 + l15, g4 * 16));
      s16x8 b1 = *(const s16x8*)(Kc + swz(ct * 16 + l15, g4 * 16 + 64));
      sacc[ct] = mfma16(sacc[ct], b0, qa0);
      sacc[ct] = mfma16(sacc[ct], b1, qa1);
    }

#pragma unroll
    for (int ct = 0; ct < 4; ++ct) {
#pragma unroll
      for (int r = 0; r < 4; ++r) {
        float e = __builtin_amdgcn_exp2f(sacc[ct][r]);
        lps += ((mw >> (ct * 16 + g4 * 4 + r)) & 1ull) ? e : 0.f;
      }
    }

    char* Kn = Kbuf + (cur ^ 1) * 8192;
    *(u16x8*)(Kn + swz(sr, ssb))      = kr0;
    *(u16x8*)(Kn + swz(sr + 32, ssb)) = kr1;
    __syncthreads();
    cur ^= 1;
  }

  lps += __shfl_xor(lps, 16);
  lps += __shfl_xor(lps, 32);
  if (g4 == 0) lpg[wv * 16 + l15] = 1.0f / lps;
}

// ---------------- main kernel: pass-1 loop + W store ----------------

__global__ __launch_bounds__(256) void attn_main_kernel(
    const unsigned short* __restrict__ Q16, const unsigned short* __restrict__ K16,
    const unsigned short* __restrict__ VT16, const unsigned long long* __restrict__ Mb,
    const float* __restrict__ lpq, float* __restrict__ Op, float* __restrict__ Wp)
{
  const int tid  = threadIdx.x;
  const int lane = tid & 63;
  const int wv   = tid >> 6;
  const int l15  = lane & 15;
  const int g4   = lane >> 4;

  const int wg = blockIdx.x;                 // 1024 blocks
  const int lg = (wg & 7) * 128 + (wg >> 3); // bijective XCD swizzle
  const int qt = lg & 31;
  const int bh = lg >> 5;
  const int b  = bh >> 4;

  __shared__ __align__(16) char lds[32768];
  char* Kbuf = lds;                          // 2 x [64 k][64 d] bf16 swz
  char* Vbuf = lds + 16384;                  // 2 x [64 d][64 s-perm] bf16 swz

  const unsigned short* Qg16 = Q16 + ((size_t)bh * S_LEN + qt * 64 + wv * 16 + l15) * D_DIM + g4 * 8;
  const unsigned short* Kg16 = K16 + (size_t)bh * S_LEN * D_DIM;
  const unsigned short* Vg   = VT16 + (size_t)bh * D_DIM * S_LEN;
  float* Og = Op + ((size_t)bh * S_LEN + qt * 64) * D_DIM;
  float* Wrow = Wp + ((size_t)bh * S_LEN + qt * 64 + wv * 16 + l15) * S_LEN;
  const unsigned long long* Mg = Mb + ((size_t)b * S_LEN + qt * 64) * SW;
  const float* lpg = lpq + (size_t)bh * S_LEN + qt * 64;

  const s16x8 qa0 = *(const s16x8*)Qg16;
  const s16x8 qa1 = *(const s16x8*)(Qg16 + 32);

  const float lpr = lpg[wv * 16 + l15];       // 1/l for this lane's W row
  float lpn[4];
#pragma unroll
  for (int r = 0; r < 4; ++r) lpn[r] = lpg[wv * 16 + g4 * 4 + r];  // for O rows

  f32x4 oacc[4];
#pragma unroll
  for (int i = 0; i < 4; ++i) oacc[i] = f32x4{0.f, 0.f, 0.f, 0.f};

  const int sr  = tid >> 3;   // 0..31: rows {sr, sr+32}
  const int ss  = tid & 7;
  const int ssb = ss * 16;

  // ---- prologue: stage tile 0 into buffer 0 ----
  {
    u16x8 k0 = *(const u16x8*)(Kg16 + (size_t)sr * D_DIM + ss * 8);
    u16x8 k1 = *(const u16x8*)(Kg16 + (size_t)(sr + 32) * D_DIM + ss * 8);
    u16x8 v0 = *(const u16x8*)(Vg + (size_t)sr * S_LEN + ss * 8);
    u16x8 v1 = *(const u16x8*)(Vg + (size_t)(sr + 32) * S_LEN + ss * 8);
    *(u16x8*)(Kbuf + swz(sr, ssb))      = k0;
    *(u16x8*)(Kbuf + swz(sr + 32, ssb)) = k1;
    *(u16x8*)(Vbuf + swz(sr, ssb))      = v0;
    *(u16x8*)(Vbuf + swz(sr + 32, ssb)) = v1;
  }
  __syncthreads();

  int cur = 0;
  for (int kt = 0; kt < NT; ++kt) {
    const int ktn = (kt + 1 < NT) ? kt + 1 : kt;
    u16x8 kr0 = *(const u16x8*)(Kg16 + (size_t)(ktn * 64 + sr) * D_DIM + ss * 8);
    u16x8 kr1 = *(const u16x8*)(Kg16 + (size_t)(ktn * 64 + sr + 32) * D_DIM + ss * 8);
    u16x8 vr0 = *(const u16x8*)(Vg + (size_t)sr * S_LEN + ktn * 64 + ss * 8);
    u16x8 vr1 = *(const u16x8*)(Vg + (size_t)(sr + 32) * S_LEN + ktn * 64 + ss * 8);
    __builtin_amdgcn_sched_barrier(0);   // pin load issue above compute

    char* Kc = Kbuf + cur * 8192;
    char* Vc = Vbuf + cur * 8192;

    const unsigned long long mw = Mg[(wv * 16 + l15) * SW + kt];

    // SWAPPED QK^T: lane holds S[k=ct*16+g4*4+r][q=qt*64+wv*16+l15]
    f32x4 sacc[4];
#pragma unroll
    for (int i = 0; i < 4; ++i) sacc[i] = f32x4{0.f, 0.f, 0.f, 0.f};
#pragma unroll
    for (int ct = 0; ct < 4; ++ct) {
      s16x8 b0 = *(const s16x8*)(Kc + swz(ct * 16 + l15, g4 * 16));
      s16x8 b1 = *(const s16x8*)(Kc + swz(ct * 16 + l15, g4 * 16 + 64));
      sacc[ct] = mfma16(sacc[ct], b0, qa0);
      sacc[ct] = mfma16(sacc[ct], b1, qa1);
    }

    // exp + mask; W store (normalized, overlaps PV); pack P frags
    unsigned pw[8];
#pragma unroll
    for (int ct = 0; ct < 4; ++ct) {
      float e0 = __builtin_amdgcn_exp2f(sacc[ct][0]);
      float e1 = __builtin_amdgcn_exp2f(sacc[ct][1]);
      float e2 = __builtin_amdgcn_exp2f(sacc[ct][2]);
      float e3 = __builtin_amdgcn_exp2f(sacc[ct][3]);
      e0 = ((mw >> (ct * 16 + g4 * 4 + 0)) & 1ull) ? e0 : 0.f;
      e1 = ((mw >> (ct * 16 + g4 * 4 + 1)) & 1ull) ? e1 : 0.f;
      e2 = ((mw >> (ct * 16 + g4 * 4 + 2)) & 1ull) ? e2 : 0.f;
      e3 = ((mw >> (ct * 16 + g4 * 4 + 3)) & 1ull) ? e3 : 0.f;
      f32x4 w = {e0 * lpr, e1 * lpr, e2 * lpr, e3 * lpr};
      __builtin_nontemporal_store(w,
          (f32x4*)(Wrow + (size_t)kt * 64 + ct * 16 + g4 * 4));
      pw[2 * ct]     = cvt_pk_bf16(e0, e1);
      pw[2 * ct + 1] = cvt_pk_bf16(e2, e3);
    }
    const s16x8 pa0 = __builtin_bit_cast(s16x8, u32x4{pw[0], pw[1], pw[2], pw[3]});
    const s16x8 pa1 = __builtin_bit_cast(s16x8, u32x4{pw[4], pw[5], pw[6], pw[7]});

    // PV: A=P (unnormalized; l folded at O store), B=V^T (sigma-permuted)
#pragma unroll
    for (int ct = 0; ct < 4; ++ct) {
      s16x8 v0 = *(const s16x8*)(Vc + swz(ct * 16 + l15, g4 * 16));
      s16x8 v1 = *(const s16x8*)(Vc + swz(ct * 16 + l15, g4 * 16 + 64));
      oacc[ct] = mfma16(oacc[ct], pa0, v0);
      oacc[ct] = mfma16(oacc[ct], pa1, v1);
    }

    char* Kn = Kbuf + (cur ^ 1) * 8192;
    char* Vn = Vbuf + (cur ^ 1) * 8192;
    *(u16x8*)(Kn + swz(sr, ssb))      = kr0;
    *(u16x8*)(Kn + swz(sr + 32, ssb)) = kr1;
    *(u16x8*)(Vn + swz(sr, ssb))      = vr0;
    *(u16x8*)(Vn + swz(sr + 32, ssb)) = vr1;
    __syncthreads();
    cur ^= 1;
  }

  // O store: oacc[ct][r] = O[q=wv*16+g4*4+r][d=ct*16+l15] (x 1/l)
#pragma unroll
  for (int ct = 0; ct < 4; ++ct)
#pragma unroll
    for (int r = 0; r < 4; ++r)
      Og[(size_t)(wv * 16 + g4 * 4 + r) * D_DIM + ct * 16 + l15] = oacc[ct][r] * lpn[r];
}

// ---------------- fallback (fp32 inputs, LDS-staged, int mask) ----------------

__global__ __launch_bounds__(256) void attn_fwd_kernel(
    const float* __restrict__ Qp, const float* __restrict__ Kp, const float* __restrict__ Vp,
    const int* __restrict__ Mi, float* __restrict__ Op, float* __restrict__ Wp)
{
  const int tid  = threadIdx.x;
  const int lane = tid & 63;
  const int wv   = tid >> 6;
  const int l15  = lane & 15;
  const int g4   = lane >> 4;

  const int wg = blockIdx.x;
  const int lg = (wg & 7) * 128 + (wg >> 3);
  const int qt = lg & 31;
  const int bh = lg >> 5;
  const int b  = bh >> 4;

  __shared__ __align__(16) char lds[32768];
  char* Qs  = lds;
  char* Ks  = lds + 8192;
  char* VTs = lds + 16384;
  char* Ps  = lds + 24576 + (wv << 11);

  const float* Qg = Qp + ((size_t)bh * S_LEN + qt * 64) * D_DIM;
  const float* Kg = Kp + (size_t)bh * S_LEN * D_DIM;
  const float* Vg = Vp + (size_t)bh * S_LEN * D_DIM;
  float* Og = Op + ((size_t)bh * S_LEN + qt * 64) * D_DIM;
  float* Wg = Wp + ((size_t)bh * S_LEN + qt * 64) * S_LEN;
  const int* Mig = Mi + ((size_t)b * S_LEN + qt * 64) * S_LEN;

  {
    const int r0 = tid >> 4;
    const int c  = (tid & 15) * 4;
#pragma unroll
    for (int i = 0; i < 4; ++i) {
      const int r = r0 + i * 16;
      float4 v = *(const float4*)(Qg + r * D_DIM + c);
      ushort4 p; p.x = f2bf(v.x); p.y = f2bf(v.y); p.z = f2bf(v.z); p.w = f2bf(v.w);
      *(ushort4*)(Qs + swz(r, c * 2)) = p;
    }
  }
  __syncthreads();
  const s16x8 qa0 = *(const s16x8*)(Qs + swz(wv * 16 + l15, g4 * 16));
  const s16x8 qa1 = *(const s16x8*)(Qs + swz(wv * 16 + l15, g4 * 16 + 64));

  f32x4 oacc[4];
#pragma unroll
  for (int i = 0; i < 4; ++i) oacc[i] = f32x4{0.f, 0.f, 0.f, 0.f};
  float lp[4] = {0.f, 0.f, 0.f, 0.f};

  const int qrow = wv * 16 + g4 * 4;

  for (int kt = 0; kt < NT; ++kt) {
    __syncthreads();
    {
      const int r0 = tid >> 4;
      const int c  = (tid & 15) * 4;
      const float* Kt = Kg + kt * 64 * D_DIM;
#pragma unroll
      for (int i = 0; i < 4; ++i) {
        const int r = r0 + i * 16;
        float4 v = *(const float4*)(Kt + r * D_DIM + c);
        ushort4 p; p.x = f2bf(v.x); p.y = f2bf(v.y); p.z = f2bf(v.z); p.w = f2bf(v.w);
        *(ushort4*)(Ks + swz(r, c * 2)) = p;
      }
      const float* Vt = Vg + kt * 64 * D_DIM;
#pragma unroll
      for (int i = 0; i < 2; ++i) {
        const int rr = (tid >> 4) * 2 + i * 32;
        float4 a  = *(const float4*)(Vt + rr * D_DIM + c);
        float4 bq = *(const float4*)(Vt + (rr + 1) * D_DIM + c);
        const float av[4] = {a.x, a.y, a.z, a.w};
        const float bv[4] = {bq.x, bq.y, bq.z, bq.w};
#pragma unroll
        for (int j = 0; j < 4; ++j) {
          unsigned pk = (unsigned)f2bf(av[j]) | ((unsigned)f2bf(bv[j]) << 16);
          *(unsigned*)(VTs + swz(c + j, rr * 2)) = pk;
        }
      }
    }
    __syncthreads();

    f32x4 sacc[4];
#pragma unroll
    for (int i = 0; i < 4; ++i) sacc[i] = f32x4{0.f, 0.f, 0.f, 0.f};
#pragma unroll
    for (int ct = 0; ct < 4; ++ct) {
      s16x8 b0 = *(const s16x8*)(Ks + swz(ct * 16 + l15, g4 * 16));
      s16x8 b1 = *(const s16x8*)(Ks + swz(ct * 16 + l15, g4 * 16 + 64));
      sacc[ct] = mfma16(sacc[ct], qa0, b0);
      sacc[ct] = mfma16(sacc[ct], qa1, b1);
    }

#pragma unroll
    for (int ct = 0; ct < 4; ++ct) {
#pragma unroll
      for (int r = 0; r < 4; ++r) {
        float e = __expf(sacc[ct][r] * 0.125f);
        bool keep = Mig[(size_t)(qrow + r) * S_LEN + kt * 64 + ct * 16 + l15] != 0;
        e = keep ? e : 0.f;
        lp[r] += e;
        *(unsigned short*)(Ps + swz(g4 * 4 + r, (ct * 16 + l15) * 2)) = f2bf(e);
      }
    }
    asm volatile("s_waitcnt lgkmcnt(0)" ::: "memory");
    __builtin_amdgcn_sched_barrier(0);

    const s16x8 pa0 = *(const s16x8*)(Ps + swz(l15, g4 * 16));
    const s16x8 pa1 = *(const s16x8*)(Ps + swz(l15, g4 * 16 + 64));
#pragma unroll
    for (int ct = 0; ct < 4; ++ct) {
      s16x8 v0 = *(const s16x8*)(VTs + swz(ct * 16 + l15, g4 * 16));
      s16x8 v1 = *(const s16x8*)(VTs + swz(ct * 16 + l15, g4 * 16 + 64));
      oacc[ct] = mfma16(oacc[ct], pa0, v0);
      oacc[ct] = mfma16(oacc[ct], pa1, v1);
    }
  }

#pragma unroll
  for (int r = 0; r < 4; ++r) {
    float v = lp[r];
    v += __shfl_xor(v, 1);
    v += __shfl_xor(v, 2);
    v += __shfl_xor(v, 4);
    v += __shfl_xor(v, 8);
    lp[r] = 1.0f / v;
  }

#pragma unroll
  for (int ct = 0; ct < 4; ++ct)
#pragma unroll
    for (int r = 0; r < 4; ++r)
      Og[(size_t)(qrow + r) * D_DIM + ct * 16 + l15] = oacc[ct][r] * lp[r];

  for (int kt = 0; kt < NT; ++kt) {
    __syncthreads();
    {
      const int r0 = tid >> 4;
      const int c  = (tid & 15) * 4;
      const float* Kt = Kg + kt * 64 * D_DIM;
#pragma unroll
      for (int i = 0; i < 4; ++i) {
        const int r = r0 + i * 16;
        float4 v = *(const float4*)(Kt + r * D_DIM + c);
        ushort4 p; p.x = f2bf(v.x); p.y = f2bf(v.y); p.z = f2bf(v.z); p.w = f2bf(v.w);
        *(ushort4*)(Ks + swz(r, c * 2)) = p;
      }
    }
    __syncthreads();

    f32x4 sacc[4];
#pragma unroll
    for (int i = 0; i < 4; ++i) sacc[i] = f32x4{0.f, 0.f, 0.f, 0.f};
#pragma unroll
    for (int ct = 0; ct < 4; ++ct) {
      s16x8 b0 = *(const s16x8*)(Ks + swz(ct * 16 + l15, g4 * 16));
      s16x8 b1 = *(const s16x8*)(Ks + swz(ct * 16 + l15, g4 * 16 + 64));
      sacc[ct] = mfma16(sacc[ct], qa0, b0);
      sacc[ct] = mfma16(sacc[ct], qa1, b1);
    }

#pragma unroll
    for (int ct = 0; ct < 4; ++ct) {
#pragma unroll
      for (int r = 0; r < 4; ++r) {
        float e = __expf(sacc[ct][r] * 0.125f);
        bool keep = Mig[(size_t)(qrow + r) * S_LEN + kt * 64 + ct * 16 + l15] != 0;
        e = keep ? e : 0.f;
        __builtin_nontemporal_store(e * lp[r],
            Wg + (size_t)(qrow + r) * S_LEN + kt * 64 + ct * 16 + l15);
      }
    }
  }
}

extern "C" void kernel_launch(void* const* d_in, const int* in_sizes, int n_in,
                              void* d_out, int out_size, void* d_ws, size_t ws_size,
                              hipStream_t stream) {
  (void)in_sizes; (void)n_in; (void)out_size;
  const float* Q   = (const float*)d_in[0];
  const float* K   = (const float*)d_in[1];
  const float* V   = (const float*)d_in[2];
  const int* mask  = (const int*)d_in[3];
  float* Out = (float*)d_out;
  float* W   = Out + (size_t)B_NUM * H_NUM * S_LEN * D_DIM;

  const size_t bits_bytes = (size_t)(B_NUM * S_LEN * S_LEN / 64) * 8;      // 1 MiB
  const size_t t16_bytes  = (size_t)B_NUM * H_NUM * S_LEN * D_DIM * 2;     // 8 MiB
  const size_t lp_bytes   = (size_t)B_NUM * H_NUM * S_LEN * 4;             // 256 KiB
  unsigned long long* bits = (unsigned long long*)d_ws;

  if (ws_size >= bits_bytes + 3 * t16_bytes + lp_bytes) {
    unsigned short* Q16 = (unsigned short*)((char*)d_ws + bits_bytes);
    unsigned short* K16 = Q16 + t16_bytes / 2;
    unsigned short* VT  = K16 + t16_bytes / 2;
    float* lpq = (float*)((char*)d_ws + bits_bytes + 3 * t16_bytes);
    prep_kernel<<<3072, 256, 0, stream>>>(Q, K, V, mask,
                                          (u16x4*)Q16, (u16x4*)K16, VT, bits);
    attn_rowsum_kernel<<<1024, 256, 0, stream>>>(Q16, K16, bits, lpq);
    attn_main_kernel<<<1024, 256, 0, stream>>>(Q16, K16, VT, bits, lpq, Out, W);
  } else {
    attn_fwd_kernel<<<1024, 256, 0, stream>>>(Q, K, V, mask, Out, W);
  }
}